// Round 15
// baseline (30.603 us; speedup 1.0000x reference)
//
#include <hip/hip_runtime.h>
#include <stdint.h>

// qint embedding gather: out[t,:] = f32(w[x[t],:]) * scales[x[t]]
//
// R15: isolate micro-variables. R13 shape (one token per block, no grid
// stride) + 128 threads/block, 8 dims/thread (2x dwordx4 load, 2x nt
// dwordx4 store). nt ONLY on stores: output is write-once (protect L2 rows
// for ~15% duplicate tokens); loads stay cacheable.
//
//   x:       [16384]        int32   (= out_size/1024)
//   weights: [50257, 1024]  int32   (int8 widened)
//   scales:  [50257]        float32
//   out:     [16384, 1024]  float32 (bit-exact f32 multiply)
//
// Traffic floor ~125 MB; fills prove 6.97 TB/s pure-write; mixed-stream
// estimate ~6 TB/s -> ~21 us + launch tail. Current 25.8; this probes the
// last ~2-3 us. If unchanged, we are at the mixed-stream plateau.

typedef float f32x4 __attribute__((ext_vector_type(4)));

__global__ __launch_bounds__(128) void qe_k(const int* __restrict__ x,
                                            const int* __restrict__ w,
                                            const float* __restrict__ scales,
                                            float* __restrict__ out) {
    const int token = blockIdx.x;
    const int t     = threadIdx.x;                   // 0..127

    // Block-uniform weight-layout sniff (free insurance).
    const int4 p = *reinterpret_cast<const int4*>(w);
    const bool wide =
        (p.x == (int)(int8_t)p.x) && (p.y == (int)(int8_t)p.y) &&
        (p.z == (int)(int8_t)p.z) && (p.w == (int)(int8_t)p.w);

    const int   idx = x[token];                      // block-uniform
    const float s   = scales[idx];

    f32x4 o0, o1;
    if (wide) {
        // int32 table: row 4096 B; thread t loads 2x16 B (independent).
        const int4* row = reinterpret_cast<const int4*>(w + (size_t)idx * 1024);
        const int4 a = row[2 * t];
        const int4 b = row[2 * t + 1];
        o0.x = (float)a.x * s;  o0.y = (float)a.y * s;
        o0.z = (float)a.z * s;  o0.w = (float)a.w * s;
        o1.x = (float)b.x * s;  o1.y = (float)b.y * s;
        o1.z = (float)b.z * s;  o1.w = (float)b.w * s;
    } else {
        // packed int8 table: row 1024 B; thread t loads 8 B.
        const int2 r = reinterpret_cast<const int2*>(
            reinterpret_cast<const int8_t*>(w) + (size_t)idx * 1024)[t];
        o0.x = (float)(int8_t)(r.x)       * s;
        o0.y = (float)(int8_t)(r.x >> 8)  * s;
        o0.z = (float)(int8_t)(r.x >> 16) * s;
        o0.w = (float)(int8_t)(r.x >> 24) * s;
        o1.x = (float)(int8_t)(r.y)       * s;
        o1.y = (float)(int8_t)(r.y >> 8)  * s;
        o1.z = (float)(int8_t)(r.y >> 16) * s;
        o1.w = (float)(int8_t)(r.y >> 24) * s;
    }

    // Write-once output: 2x nontemporal dwordx4.
    f32x4* op = reinterpret_cast<f32x4*>(out + (size_t)token * 1024);
    __builtin_nontemporal_store(o0, op + 2 * t);
    __builtin_nontemporal_store(o1, op + 2 * t + 1);
}

extern "C" void kernel_launch(void* const* d_in, const int* in_sizes, int n_in,
                              void* d_out, int out_size, void* d_ws, size_t ws_size,
                              hipStream_t stream) {
    const int n_tokens = out_size / 1024;            // 16384
    if (n_tokens <= 0) return;

    // Bind inputs by element count (robust to ordering).
    int iw = 0;
    for (int i = 1; i < n_in; ++i)
        if (in_sizes[i] > in_sizes[iw]) iw = i;
    int ix = -1, is = -1;
    for (int i = 0; i < n_in; ++i) {
        if (i == iw) continue;
        if (in_sizes[i] == n_tokens && ix < 0) ix = i; else is = i;
    }
    if (ix < 0) ix = (iw == 0) ? 1 : 0;
    if (is < 0) is = 3 - ix - iw;

    qe_k<<<n_tokens, 128, 0, stream>>>((const int*)d_in[ix], (const int*)d_in[iw],
                                       (const float*)d_in[is], (float*)d_out);
}

// Round 16
// 25.443 us; speedup vs baseline: 1.2028x; 1.2028x over previous
//
#include <hip/hip_runtime.h>
#include <stdint.h>

// qint embedding gather: out[t,:] = f32(w[x[t],:]) * scales[x[t]]
//
// R16 = R13 (best: 25.8 us) minus the dtype-sniff dependent load.
// Weights layout fixed as int32-widened int8: proven by in_npz=78.7MB
// (packed int8 caps at ~52MB), the round-2..12 byte-level forensics, and
// R13 passing bit-exact. Dropping the sniff removes one serial L2 hop +
// branch from every block's startup chain (16384 small blocks pay it).
//
//   x:       [16384]        int32   (= out_size/1024)
//   weights: [50257, 1024]  int32
//   scales:  [50257]        float32
//   out:     [16384, 1024]  float32 (bit-exact f32 multiply)
//
// One 256-thread block per token; thread t covers dims [4t, 4t+4):
//   dwordx4 int32 load -> 4x (cvt_f32_i32 + mul) -> dwordx4 f32 store.
// Traffic ~125 MB; mixed-stream ceiling ~5.5-6 TB/s -> 21-23 us floor.

__global__ __launch_bounds__(256) void qe_k(const int* __restrict__ x,
                                            const int* __restrict__ w,
                                            const float* __restrict__ scales,
                                            float* __restrict__ out) {
    const int token = blockIdx.x;
    const int t     = threadIdx.x;                   // 0..255

    const int   idx = x[token];                      // block-uniform
    const float s   = scales[idx];                   // issues parallel to row load

    const int4 v = reinterpret_cast<const int4*>(w + (size_t)idx * 1024)[t];

    float4 o;
    o.x = (float)v.x * s;
    o.y = (float)v.y * s;
    o.z = (float)v.z * s;
    o.w = (float)v.w * s;

    reinterpret_cast<float4*>(out + (size_t)token * 1024)[t] = o;
}

extern "C" void kernel_launch(void* const* d_in, const int* in_sizes, int n_in,
                              void* d_out, int out_size, void* d_ws, size_t ws_size,
                              hipStream_t stream) {
    const int n_tokens = out_size / 1024;            // 16384
    if (n_tokens <= 0) return;

    // Bind inputs by element count (robust to ordering):
    // weights = largest; x = the one sized n_tokens; scales = remaining.
    int iw = 0;
    for (int i = 1; i < n_in; ++i)
        if (in_sizes[i] > in_sizes[iw]) iw = i;
    int ix = -1, is = -1;
    for (int i = 0; i < n_in; ++i) {
        if (i == iw) continue;
        if (in_sizes[i] == n_tokens && ix < 0) ix = i; else is = i;
    }
    if (ix < 0) ix = (iw == 0) ? 1 : 0;
    if (is < 0) is = 3 - ix - iw;

    qe_k<<<n_tokens, 256, 0, stream>>>((const int*)d_in[ix], (const int*)d_in[iw],
                                       (const float*)d_in[is], (float*)d_out);
}